// Round 9
// baseline (299.265 us; speedup 1.0000x reference)
//
#include <hip/hip_runtime.h>

typedef unsigned short u16;
typedef __bf16 bf16x8 __attribute__((ext_vector_type(8)));
typedef float f32x4 __attribute__((ext_vector_type(4)));

#define MFMA(a, b, c) __builtin_amdgcn_mfma_f32_16x16x32_bf16(a, b, c, 0, 0, 0)

// Constants: B=4, H=64, W=128, D=128, NS=2, hh=32, ww=64, sh=16, sw=32,
// L=2048, 16 windows, 32768 rows total.

__device__ __forceinline__ u16 f2b(float f) {
  unsigned u = __builtin_bit_cast(unsigned, f);
  u += 0x7fffu + ((u >> 16) & 1u);
  return (u16)(u >> 16);
}
__device__ __forceinline__ float b2f(u16 h) {
  unsigned u = (unsigned)h << 16;
  return __builtin_bit_cast(float, u);
}
__device__ __forceinline__ void glds16(const u16* g, u16* l) {
  __builtin_amdgcn_global_load_lds((const __attribute__((address_space(1))) void*)g,
                                   (__attribute__((address_space(3))) void*)l, 16, 0, 0);
}
// gelu with branch-free erf (A&S 7.1.26, |err|<1.5e-7 — invisible after bf16 round).
__device__ __forceinline__ float fast_gelu(float x) {
  const float z = fabsf(x) * 0.70710678118654752f;
  const float t = 1.0f / (1.0f + 0.3275911f * z);
  const float poly =
      t * (0.254829592f +
           t * (-0.284496736f +
                t * (1.421413741f + t * (-1.453152027f + t * 1.061405429f))));
  const float e = exp2f(-z * z * 1.4426950408889634f);
  const float erfz = 1.0f - poly * e;
  const float s = (x >= 0.f) ? erfz : -erfz;
  return 0.5f * x * (1.0f + s);
}

// ---------------- workspace layout (bytes) ----------------
#define QW_OFF   ((size_t)0)
#define KW_OFF   ((size_t)8 << 20)
#define VBUF_OFF ((size_t)16 << 20)
#define O1_OFF   ((size_t)24 << 20)   // bf16 normalized partials, 8MB
#define O2_OFF   ((size_t)40 << 20)
#define SRCB_OFF ((size_t)64 << 20)
#define L1_OFF   ((size_t)80 << 20)
#define L2P_OFF  (((size_t)80 << 20) + 131072)
#define WQT_OFF  (((size_t)80 << 20) + 262144)
#define WKT_OFF  (WQT_OFF + 32768)
#define WVT_OFF  (WQT_OFF + 65536)
#define WMT_OFF  (WQT_OFF + 98304)
#define W1T_OFF  (WQT_OFF + 131072)
#define W2T_OFF  (WQT_OFF + 655360)

// ---------------- kernel 0: transpose weights to bf16 [n][k]; scale folded into Wq ----
__global__ void k_prep(const float* __restrict__ wq, const float* __restrict__ wk,
                       const float* __restrict__ wv, const float* __restrict__ wm,
                       const float* __restrict__ w1, const float* __restrict__ w2,
                       u16* __restrict__ wqt, u16* __restrict__ wkt,
                       u16* __restrict__ wvt, u16* __restrict__ wmt,
                       u16* __restrict__ w1t, u16* __restrict__ w2t) {
  int t = blockIdx.x * 256 + threadIdx.x;
  if (t < 65536) {
    int m = t >> 14, loc = t & 16383;
    int n = loc >> 7, k = loc & 127;
    const float* s = (m == 0) ? wq : (m == 1) ? wk : (m == 2) ? wv : wm;
    u16* d = (m == 0) ? wqt : (m == 1) ? wkt : (m == 2) ? wvt : wmt;
    const float sc = (m == 0) ? 0.08838834764831845f : 1.0f;
    d[n * 128 + k] = f2b(s[k * 128 + n] * sc);
  } else if (t < 65536 + 262144) {
    int loc = t - 65536;
    int n = loc >> 8, k = loc & 255;
    w1t[n * 256 + k] = f2b(w1[k * 1024 + n]);
  } else if (t < 65536 + 262144 + 131072) {
    int loc = t - 327680;
    int n = loc >> 10, k = loc & 1023;
    w2t[n * 1024 + k] = f2b(w2[k * 128 + n]);
  }
}

// ---------------- kernel 1: QKV projection (R4 structure; 3 blocks/CU) ---------------
__global__ __launch_bounds__(256, 3)
void k_qkv(const float* __restrict__ src,
           const u16* __restrict__ wtq, const u16* __restrict__ wtk,
           const u16* __restrict__ wtv,
           u16* __restrict__ qw, u16* __restrict__ kw, u16* __restrict__ vbuf,
           u16* __restrict__ srcb) {
  __shared__ __align__(16) u16 At[64 * 136];
  __shared__ __align__(16) u16 Bt[128 * 136];
  const int tid = threadIdx.x, bid = blockIdx.x;
  const int lane = tid & 63, wid = tid >> 6;
  const int l15 = lane & 15, quad = lane >> 4;

  {  // stage A tile (64 windowed rows x 128) + write srcb at original rows
    const int row = tid >> 2, part = tid & 3;
    const int t = bid * 64 + row;
    const int g = t >> 11, p = t & 2047;
    const int b = g >> 2, wi = (g >> 1) & 1, wj = g & 1;
    const int ii = p >> 6, jj = p & 63;
    const int y = (wi * 32 + ii + 16) & 63;
    const int x = (wj * 64 + jj + 32) & 127;
    const int srow = b * 8192 + y * 128 + x;
    const float4* sp = (const float4*)(src + srow * 128) + part * 8;
    u16* lp = &At[row * 136 + part * 32];
    u16* gp = srcb + srow * 128 + part * 32;
#pragma unroll
    for (int q = 0; q < 8; ++q) {
      float4 v = sp[q];
      ushort4 h = make_ushort4(f2b(v.x), f2b(v.y), f2b(v.z), f2b(v.w));
      *(ushort4*)(lp + q * 4) = h;
      *(ushort4*)(gp + q * 4) = h;
    }
  }
  __syncthreads();

  bf16x8 afrag[4];
  const int arow = wid * 16 + l15;
#pragma unroll
  for (int kk = 0; kk < 4; ++kk)
    afrag[kk] = *(const bf16x8*)&At[arow * 136 + kk * 32 + quad * 8];

  const f32x4 fz = {0.f, 0.f, 0.f, 0.f};
#pragma unroll 1
  for (int m = 0; m < 3; ++m) {
    const u16* wp = (m == 0) ? wtq : (m == 1) ? wtk : wtv;
    {  // stage B: weight [n][k] 128x128 bf16
      const int n = tid >> 1, half = tid & 1;
      const uint4* sp = (const uint4*)(wp + n * 128 + half * 64);
      uint4* dp = (uint4*)&Bt[n * 136 + half * 64];
#pragma unroll
      for (int q = 0; q < 8; ++q) dp[q] = sp[q];
    }
    __syncthreads();
    f32x4 acc[8];
#pragma unroll
    for (int nt = 0; nt < 8; ++nt) acc[nt] = fz;
#pragma unroll
    for (int kk = 0; kk < 4; ++kk) {
#pragma unroll
      for (int nt = 0; nt < 8; ++nt) {
        bf16x8 bfr = *(const bf16x8*)&Bt[(nt * 16 + l15) * 136 + kk * 32 + quad * 8];
        acc[nt] = MFMA(afrag[kk], bfr, acc[nt]);
      }
    }
    const int t0 = bid * 64 + wid * 16 + quad * 4;
    if (m < 2) {
      u16* dst = (m == 0) ? qw : kw;
#pragma unroll
      for (int nt = 0; nt < 8; ++nt) {
        const int d = nt * 16 + l15;
#pragma unroll
        for (int r = 0; r < 4; ++r) dst[(t0 + r) * 128 + d] = f2b(acc[nt][r]);
      }
    } else {
      const int g = bid >> 5;
      const int p0 = t0 & 2047;
#pragma unroll
      for (int nt = 0; nt < 8; ++nt) {
        const int d = nt * 16 + l15;
        ushort4 hv = make_ushort4(f2b(acc[nt][0]), f2b(acc[nt][1]),
                                  f2b(acc[nt][2]), f2b(acc[nt][3]));
        *(ushort4*)&vbuf[g * 262144 + d * 2048 + p0] = hv;
      }
    }
    __syncthreads();
  }
}

// ---------------- kernel 2: attention (R4 structure; R9: setprio on MFMA clusters) ---
__global__ __launch_bounds__(256, 2)
void k_attn(const u16* __restrict__ qw, const u16* __restrict__ kw,
            const u16* __restrict__ vbuf, const float* __restrict__ mask,
            u16* __restrict__ o1, u16* __restrict__ o2,
            float* __restrict__ l1, float* __restrict__ l2) {
  __shared__ __align__(16) u16 Kt[2][64 * 128];  // [key][d], block swizzle c^=(key&15)
  __shared__ __align__(16) u16 Vt[2][128 * 64];  // [d][key], block swizzle c^=(d&7)
  __shared__ __align__(16) u16 Pt[128 * 40];     // per-wave P (32 rows x 32 keys)
  const int tid = threadIdx.x;
  const int bid = (blockIdx.x & 7) * 64 + (blockIdx.x >> 3);
  const int lane = tid & 63, wid = tid >> 6;
  const int l15 = lane & 15, quad = lane >> 4;
  const int b = bid & 3, w = (bid >> 2) & 3, half = (bid >> 4) & 1, qb = bid >> 5;
  const int g = b * 4 + w;
  const int k0 = half * 1024;
  const u16* kbase = kw + g * 262144 + k0 * 128;
  const u16* vbase = vbuf + g * 262144 + k0;
  const int qrow0 = qb * 128 + wid * 32;  // wave's first q-row within g
  const float* mlane = mask + (size_t)w * 4194304 + (size_t)(qrow0 + quad * 4) * 2048 + k0 + l15;

  // glds: per-thread source offsets (elems) + wave-uniform dest bases (elems)
  int offk[4], offv[4], dstb[4];
#pragma unroll
  for (int j = 0; j < 4; ++j) {
    const int s = wid * 256 + j * 64 + lane;         // linear 16B-block id, 0..1023
    const int rk = s >> 4, bk = (s & 15) ^ (rk & 15);
    offk[j] = rk * 128 + bk * 8;
    const int dv = s >> 3, bv = (s & 7) ^ (dv & 7);
    offv[j] = dv * 2048 + bv * 8;
    dstb[j] = (wid * 256 + j * 64) * 8;              // + lane*16B by hardware
  }

  bf16x8 qfrag[2][4];
#pragma unroll
  for (int qs = 0; qs < 2; ++qs) {
    const u16* qp = qw + g * 262144 + (qrow0 + qs * 16 + l15) * 128 + quad * 8;
#pragma unroll
    for (int kk = 0; kk < 4; ++kk) qfrag[qs][kk] = *(const bf16x8*)(qp + kk * 32);
  }
  const f32x4 fz = {0.f, 0.f, 0.f, 0.f};
  f32x4 o[2][8];
#pragma unroll
  for (int qs = 0; qs < 2; ++qs)
#pragma unroll
    for (int nt = 0; nt < 8; ++nt) o[qs][nt] = fz;
  float lr[2][4] = {{0.f, 0.f, 0.f, 0.f}, {0.f, 0.f, 0.f, 0.f}};
  const float L2E = 1.4426950408889634f;

  // preload tile 0 + mask phase 0 (mask double-buffered at 32-key phase granularity)
#pragma unroll
  for (int j = 0; j < 4; ++j) {
    glds16(kbase + offk[j], &Kt[0][dstb[j]]);
    glds16(vbase + offv[j], &Vt[0][dstb[j]]);
  }
  float mpf[16];
#pragma unroll
  for (int qs = 0; qs < 2; ++qs)
#pragma unroll
    for (int ntl = 0; ntl < 2; ++ntl)
#pragma unroll
      for (int r = 0; r < 4; ++r)
        mpf[qs * 8 + ntl * 4 + r] = mlane[(qs * 16 + r) * 2048 + ntl * 16];

#pragma unroll 1
  for (int kt = 0; kt < 16; ++kt) {
    const int p = kt & 1;
    __syncthreads();  // drains glds(kt) [issued a full iter ago]; prior-iter reads done
    if (kt < 15) {    // prefetch tile kt+1 into the other buffer; overlaps this compute
      const u16* kb = kbase + (kt + 1) * 8192;
      const u16* vb = vbase + (kt + 1) * 64;
#pragma unroll
      for (int j = 0; j < 4; ++j) {
        glds16(kb + offk[j], &Kt[p ^ 1][dstb[j]]);
        glds16(vb + offv[j], &Vt[p ^ 1][dstb[j]]);
      }
    }
#pragma unroll
    for (int ks = 0; ks < 2; ++ks) {
      // prefetch mask for the NEXT 32-key phase while computing this one
      float mn[16];
      const bool hasn = (kt < 15) || (ks == 0);
      const int ncol = kt * 64 + 32 + ks * 32;
      if (hasn) {
#pragma unroll
        for (int qs = 0; qs < 2; ++qs)
#pragma unroll
          for (int ntl = 0; ntl < 2; ++ntl)
#pragma unroll
            for (int r = 0; r < 4; ++r)
              mn[qs * 8 + ntl * 4 + r] = mlane[(qs * 16 + r) * 2048 + ncol + ntl * 16];
      }
      // S = Q K^T + mask (C-init from prefetched regs; Q pre-scaled)
      f32x4 s[2][2];
#pragma unroll
      for (int qs = 0; qs < 2; ++qs)
#pragma unroll
        for (int ntl = 0; ntl < 2; ++ntl)
#pragma unroll
          for (int r = 0; r < 4; ++r) s[qs][ntl][r] = mpf[qs * 8 + ntl * 4 + r];
      __builtin_amdgcn_s_setprio(1);
#pragma unroll
      for (int kk = 0; kk < 4; ++kk)
#pragma unroll
        for (int ntl = 0; ntl < 2; ++ntl) {
          bf16x8 kfr = *(const bf16x8*)&Kt[p][(ks * 32 + ntl * 16 + l15) * 128 +
                                             (((kk * 4 + quad) ^ l15) * 8)];
          s[0][ntl] = MFMA(qfrag[0][kk], kfr, s[0][ntl]);
          s[1][ntl] = MFMA(qfrag[1][kk], kfr, s[1][ntl]);
        }
      __builtin_amdgcn_s_setprio(0);
      // fixed-max softmax: p = e^s; per-lane partial row-sums (reduced in epilogue)
#pragma unroll
      for (int qs = 0; qs < 2; ++qs)
#pragma unroll
        for (int ntl = 0; ntl < 2; ++ntl)
#pragma unroll
          for (int r = 0; r < 4; ++r) {
            const float pv = exp2f(s[qs][ntl][r] * L2E);
            lr[qs][r] += pv;
            Pt[(wid * 32 + qs * 16 + quad * 4 + r) * 40 + ntl * 16 + l15] = f2b(pv);
          }
      // O += P @ V (P via per-wave LDS round-trip, C-layout -> A-layout)
      bf16x8 pf0 = *(const bf16x8*)&Pt[(wid * 32 + l15) * 40 + quad * 8];
      bf16x8 pf1 = *(const bf16x8*)&Pt[(wid * 32 + 16 + l15) * 40 + quad * 8];
      __builtin_amdgcn_s_setprio(1);
#pragma unroll
      for (int nt = 0; nt < 8; ++nt) {
        bf16x8 vfr = *(const bf16x8*)&Vt[p][(nt * 16 + l15) * 64 +
                                            (((ks * 4 + quad) ^ (l15 & 7)) * 8)];
        o[0][nt] = MFMA(pf0, vfr, o[0][nt]);
        o[1][nt] = MFMA(pf1, vfr, o[1][nt]);
      }
      __builtin_amdgcn_s_setprio(0);
      if (hasn) {
#pragma unroll
        for (int i = 0; i < 16; ++i) mpf[i] = mn[i];
      }
    }
  }

  // epilogue: reduce l across the 16 lanes, normalize partial, store bf16
#pragma unroll
  for (int off = 1; off < 16; off <<= 1)
#pragma unroll
    for (int qs = 0; qs < 2; ++qs)
#pragma unroll
      for (int r = 0; r < 4; ++r) lr[qs][r] += __shfl_xor(lr[qs][r], off, 16);
  u16* op = half ? o2 : o1;
  float* lp = half ? l2 : l1;
#pragma unroll
  for (int qs = 0; qs < 2; ++qs) {
    const int t0 = g * 2048 + qrow0 + qs * 16 + quad * 4;
#pragma unroll
    for (int r = 0; r < 4; ++r) {
      const float inv = 1.f / lr[qs][r];
#pragma unroll
      for (int nt = 0; nt < 8; ++nt)
        op[(size_t)(t0 + r) * 128 + nt * 16 + l15] = f2b(o[qs][nt][r] * inv);
      if (l15 == 0) lp[t0 + r] = lr[qs][r];
    }
  }
}

// ---------------- kernel 3: FUSED wmln+mlp (R9: 3 blocks/CU + stride-140 phase 1) ----
// out = src + LN2(gelu([src || LN1(merge(o1,o2)@Wm)] @ W1) @ W2).
__global__ __launch_bounds__(256, 3)
void k_mlp(const u16* __restrict__ o1, const u16* __restrict__ o2,
           const float* __restrict__ l1, const float* __restrict__ l2,
           const u16* __restrict__ wmt, const float* __restrict__ g1,
           const float* __restrict__ b1,
           const u16* __restrict__ srcb,
           const u16* __restrict__ w1t, const u16* __restrict__ w2t,
           const float* __restrict__ g2, const float* __restrict__ b2,
           const float* __restrict__ src, float* __restrict__ out) {
  __shared__ __align__(16) u16 lds[27136];          // 53KB overlay; x3 = 159KB/CU
  u16* Mt  = lds;                                   // ph1: 64*140 (8960), stride 140
  u16* BtW = lds + 8960;                            // ph1: 128*140 (17920), stride 140
  u16* Bt1 = lds;                                   // ph2: 2*32*256 (16384)
  u16* Bt2 = lds + 16384;                           // ph2: 2*128*32 (8192)
  u16* Ht  = lds + 24576;                           // ph2: 64*40 (2560)
  const int tid = threadIdx.x, bid = blockIdx.x;
  const int lane = tid & 63, wid = tid >> 6;
  const int l15 = lane & 15, quad = lane >> 4;
  const f32x4 fz = {0.f, 0.f, 0.f, 0.f};

  // A-frags [src half] issued early (global, spatial rows)
  bf16x8 afrag[8];
  {
    const int t_sp = bid * 64 + wid * 16 + l15;
    const u16* sp = srcb + (size_t)t_sp * 128 + quad * 8;
#pragma unroll
    for (int kk = 0; kk < 4; ++kk) afrag[kk] = *(const bf16x8*)(sp + kk * 32);
  }

  // ---- phase 1: stage merged message rows + Wm (stride 140: 70 u32 ≡ 6 mod 32,
  // 16 distinct write banks vs 8-way conflicts at stride 136) ----
  {
    const int row = tid >> 2, part = tid & 3;
    const int t_sp = bid * 64 + row;
    // spatial -> window row (inverse of k_qkv's to_windows)
    const int bb = t_sp >> 13, rem = t_sp & 8191;
    const int y = rem >> 7, x = rem & 127;
    const int u = (y + 48) & 63, v = (x + 96) & 127;
    const int wrow = (bb * 4 + (u >> 5) * 2 + (v >> 6)) * 2048 + (u & 31) * 64 + (v & 63);
    const float la = l1[wrow], lb = l2[wrow];
    const float wA = la / (la + lb), wB = lb / (la + lb);
    const u16* p1 = o1 + (size_t)wrow * 128 + part * 32;
    const u16* p2 = o2 + (size_t)wrow * 128 + part * 32;
    u16* lp = &Mt[row * 140 + part * 32];
#pragma unroll
    for (int q = 0; q < 4; ++q) {
      ushort4 xa = *(const ushort4*)(p1 + q * 8);
      ushort4 xb = *(const ushort4*)(p1 + q * 8 + 4);
      ushort4 ya = *(const ushort4*)(p2 + q * 8);
      ushort4 yb = *(const ushort4*)(p2 + q * 8 + 4);
      ushort4 ha = make_ushort4(f2b(b2f(xa.x) * wA + b2f(ya.x) * wB),
                                f2b(b2f(xa.y) * wA + b2f(ya.y) * wB),
                                f2b(b2f(xa.z) * wA + b2f(ya.z) * wB),
                                f2b(b2f(xa.w) * wA + b2f(ya.w) * wB));
      ushort4 hb = make_ushort4(f2b(b2f(xb.x) * wA + b2f(yb.x) * wB),
                                f2b(b2f(xb.y) * wA + b2f(yb.y) * wB),
                                f2b(b2f(xb.z) * wA + b2f(yb.z) * wB),
                                f2b(b2f(xb.w) * wA + b2f(yb.w) * wB));
      *(ushort4*)(lp + q * 8) = ha;
      *(ushort4*)(lp + q * 8 + 4) = hb;
    }
  }
  {
    const int n = tid >> 1, half = tid & 1;
    const uint4* sp = (const uint4*)(wmt + n * 128 + half * 64);
    uint4* dp = (uint4*)&BtW[n * 140 + half * 64];
#pragma unroll
    for (int q = 0; q < 8; ++q) dp[q] = sp[q];
  }
  __syncthreads();

  // Wm GEMM (16 rows x 128 cols per wave) + LN1
  {
    const int arow = wid * 16 + l15;
    bf16x8 am[4];
#pragma unroll
    for (int kk = 0; kk < 4; ++kk)
      am[kk] = *(const bf16x8*)&Mt[arow * 140 + kk * 32 + quad * 8];
    f32x4 acc[8];
#pragma unroll
    for (int nt = 0; nt < 8; ++nt) acc[nt] = fz;
#pragma unroll
    for (int kk = 0; kk < 4; ++kk)
#pragma unroll
      for (int nt = 0; nt < 8; ++nt) {
        bf16x8 bfr = *(const bf16x8*)&BtW[(nt * 16 + l15) * 140 + kk * 32 + quad * 8];
        acc[nt] = MFMA(am[kk], bfr, acc[nt]);
      }
    float sum[4] = {0, 0, 0, 0}, sq[4] = {0, 0, 0, 0};
#pragma unroll
    for (int nt = 0; nt < 8; ++nt)
#pragma unroll
      for (int r = 0; r < 4; ++r) {
        const float v = acc[nt][r];
        sum[r] += v;
        sq[r] += v * v;
      }
#pragma unroll
    for (int off = 1; off < 16; off <<= 1)
#pragma unroll
      for (int r = 0; r < 4; ++r) {
        sum[r] += __shfl_xor(sum[r], off, 16);
        sq[r] += __shfl_xor(sq[r], off, 16);
      }
    float mean[4], rstd[4];
#pragma unroll
    for (int r = 0; r < 4; ++r) {
      mean[r] = sum[r] * (1.f / 128.f);
      const float var = sq[r] * (1.f / 128.f) - mean[r] * mean[r];
      rstd[r] = rsqrtf(var + 1e-5f);
    }
    // write LN'd msg bf16 back into Mt (wave-private rows; MFMA reads already done)
#pragma unroll
    for (int nt = 0; nt < 8; ++nt) {
      const int d = nt * 16 + l15;
      const float gg = g1[d], bb = b1[d];
#pragma unroll
      for (int r = 0; r < 4; ++r)
        Mt[(wid * 16 + quad * 4 + r) * 140 + d] =
            f2b((acc[nt][r] - mean[r]) * rstd[r] * gg + bb);
    }
    // read msg A-frags (own rows; compiler orders via lgkmcnt)
#pragma unroll
    for (int kk = 0; kk < 4; ++kk)
      afrag[kk + 4] = *(const bf16x8*)&Mt[arow * 140 + kk * 32 + quad * 8];
  }
  __syncthreads();  // all msg A-frag reads done before phase-2 staging clobbers lds

  // ---- phase 2: MLP dbuf loop (R4-proven) ----
  int off1[4], db1[4], off2[2], db2[2];
#pragma unroll
  for (int j = 0; j < 4; ++j) {
    const int s = wid * 256 + j * 64 + lane;   // 16B-block id 0..1023
    const int r = s >> 5, c = s & 31;          // r: W1 row (hidden col), c: k-block
    off1[j] = r * 256 + (c ^ (r & 15)) * 8;
    db1[j] = (wid * 256 + j * 64) * 8;
  }
#pragma unroll
  for (int j = 0; j < 2; ++j) {
    const int s = wid * 128 + j * 64 + lane;   // 16B-block id 0..511
    const int r = s >> 2, c = s & 3;           // r: W2 row (d col), c: k-block
    off2[j] = r * 1024 + (c ^ (r & 3)) * 8;
    db2[j] = (wid * 128 + j * 64) * 8;
  }
  f32x4 oacc[8];
#pragma unroll
  for (int nt = 0; nt < 8; ++nt) oacc[nt] = fz;

  // prologue: stage chunk 0 into buffer 0
#pragma unroll
  for (int j = 0; j < 4; ++j) glds16(w1t + off1[j], &Bt1[db1[j]]);
#pragma unroll
  for (int j = 0; j < 2; ++j) glds16(w2t + off2[j], &Bt2[db2[j]]);

#pragma unroll 1
  for (int hc = 0; hc < 32; ++hc) {
    const int p = hc & 1;
    __syncthreads();  // drains glds(hc) [issued an iter ago]; prior-iter reads done
    if (hc < 31) {    // prefetch chunk hc+1 into the other buffer; overlaps compute
#pragma unroll
      for (int j = 0; j < 4; ++j)
        glds16(w1t + (hc + 1) * 8192 + off1[j], &Bt1[((p ^ 1) * 8192) + db1[j]]);
#pragma unroll
      for (int j = 0; j < 2; ++j)
        glds16(w2t + (hc + 1) * 32 + off2[j], &Bt2[((p ^ 1) * 4096) + db2[j]]);
    }

    // H chunk = A @ W1c  (16 rows x 32 cols per wave)
    f32x4 hacc[2];
    hacc[0] = fz;
    hacc[1] = fz;
#pragma unroll
    for (int kk = 0; kk < 8; ++kk)
#pragma unroll
      for (int nt = 0; nt < 2; ++nt) {
        bf16x8 b1fr = *(const bf16x8*)&Bt1[p * 8192 + (nt * 16 + l15) * 256 +
                                           (((kk * 4 + quad) ^ l15) * 8)];
        hacc[nt] = MFMA(afrag[kk], b1fr, hacc[nt]);
      }
    // fast_gelu -> bf16 Ht (per-wave rows; no barrier needed)
#pragma unroll
    for (int nt = 0; nt < 2; ++nt)
#pragma unroll
      for (int r = 0; r < 4; ++r) {
        const float y = fast_gelu(hacc[nt][r]);
        Ht[(wid * 16 + quad * 4 + r) * 40 + nt * 16 + l15] = f2b(y);
      }
    // out += Ht @ W2c
    bf16x8 hf = *(const bf16x8*)&Ht[(wid * 16 + l15) * 40 + quad * 8];
#pragma unroll
    for (int nt = 0; nt < 8; ++nt) {
      bf16x8 b2fr = *(const bf16x8*)&Bt2[p * 4096 + (nt * 16 + l15) * 32 +
                                         ((quad ^ (l15 & 3)) * 8)];
      oacc[nt] = MFMA(hf, b2fr, oacc[nt]);
    }
  }

  // LN2(g2,b2) + residual epilogue (fp32 out)
  float sum[4] = {0, 0, 0, 0}, sq[4] = {0, 0, 0, 0};
#pragma unroll
  for (int nt = 0; nt < 8; ++nt)
#pragma unroll
    for (int r = 0; r < 4; ++r) {
      const float v = oacc[nt][r];
      sum[r] += v;
      sq[r] += v * v;
    }
#pragma unroll
  for (int off = 1; off < 16; off <<= 1)
#pragma unroll
    for (int r = 0; r < 4; ++r) {
      sum[r] += __shfl_xor(sum[r], off, 16);
      sq[r] += __shfl_xor(sq[r], off, 16);
    }
  float mean[4], rstd[4];
#pragma unroll
  for (int r = 0; r < 4; ++r) {
    mean[r] = sum[r] * (1.f / 128.f);
    const float var = sq[r] * (1.f / 128.f) - mean[r] * mean[r];
    rstd[r] = rsqrtf(var + 1e-5f);
  }
  const int t0 = bid * 64 + wid * 16 + quad * 4;
#pragma unroll
  for (int nt = 0; nt < 8; ++nt) {
    const int d = nt * 16 + l15;
    const float gg = g2[d], bb = b2[d];
#pragma unroll
    for (int r = 0; r < 4; ++r) {
      const int idx = (t0 + r) * 128 + d;
      out[idx] = src[idx] + (oacc[nt][r] - mean[r]) * rstd[r] * gg + bb;
    }
  }
}

extern "C" void kernel_launch(void* const* d_in, const int* in_sizes, int n_in,
                              void* d_out, int out_size, void* d_ws, size_t ws_size,
                              hipStream_t stream) {
  const float* src  = (const float*)d_in[0];
  const float* mask = (const float*)d_in[2];
  const float* Wq = (const float*)d_in[8];
  const float* Wk = (const float*)d_in[9];
  const float* Wv = (const float*)d_in[10];
  const float* Wm = (const float*)d_in[11];
  const float* g1 = (const float*)d_in[12];
  const float* b1 = (const float*)d_in[13];
  const float* W1 = (const float*)d_in[14];
  const float* W2 = (const float*)d_in[15];
  const float* g2 = (const float*)d_in[16];
  const float* b2 = (const float*)d_in[17];
  char* ws = (char*)d_ws;
  u16* qw   = (u16*)(ws + QW_OFF);
  u16* kw   = (u16*)(ws + KW_OFF);
  u16* vbuf = (u16*)(ws + VBUF_OFF);
  u16* o1   = (u16*)(ws + O1_OFF);
  u16* o2   = (u16*)(ws + O2_OFF);
  float* l1 = (float*)(ws + L1_OFF);
  float* l2 = (float*)(ws + L2P_OFF);
  u16* srcb = (u16*)(ws + SRCB_OFF);
  u16* wqt = (u16*)(ws + WQT_OFF);
  u16* wkt = (u16*)(ws + WKT_OFF);
  u16* wvt = (u16*)(ws + WVT_OFF);
  u16* wmt = (u16*)(ws + WMT_OFF);
  u16* w1t = (u16*)(ws + W1T_OFF);
  u16* w2t = (u16*)(ws + W2T_OFF);

  k_prep<<<1792, 256, 0, stream>>>(Wq, Wk, Wv, Wm, W1, W2, wqt, wkt, wvt, wmt, w1t, w2t);
  k_qkv<<<512, 256, 0, stream>>>(src, wqt, wkt, wvt, qw, kw, vbuf, srcb);
  k_attn<<<512, 256, 0, stream>>>(qw, kw, vbuf, mask, o1, o2, l1, l2);
  k_mlp<<<512, 256, 0, stream>>>(o1, o2, l1, l2, wmt, g1, b1, srcb, w1t, w2t,
                                 g2, b2, src, (float*)d_out);
}

// Round 10
// 286.144 us; speedup vs baseline: 1.0459x; 1.0459x over previous
//
#include <hip/hip_runtime.h>

typedef unsigned short u16;
typedef __bf16 bf16x8 __attribute__((ext_vector_type(8)));
typedef float f32x4 __attribute__((ext_vector_type(4)));

#define MFMA(a, b, c) __builtin_amdgcn_mfma_f32_16x16x32_bf16(a, b, c, 0, 0, 0)

// Constants: B=4, H=64, W=128, D=128, NS=2, hh=32, ww=64, sh=16, sw=32,
// L=2048, 16 windows, 32768 rows total.

__device__ __forceinline__ u16 f2b(float f) {
  unsigned u = __builtin_bit_cast(unsigned, f);
  u += 0x7fffu + ((u >> 16) & 1u);
  return (u16)(u >> 16);
}
__device__ __forceinline__ float b2f(u16 h) {
  unsigned u = (unsigned)h << 16;
  return __builtin_bit_cast(float, u);
}
__device__ __forceinline__ void glds16(const u16* g, u16* l) {
  __builtin_amdgcn_global_load_lds((const __attribute__((address_space(1))) void*)g,
                                   (__attribute__((address_space(3))) void*)l, 16, 0, 0);
}
// gelu with branch-free erf (A&S 7.1.26, |err|<1.5e-7 — invisible after bf16 round).
__device__ __forceinline__ float fast_gelu(float x) {
  const float z = fabsf(x) * 0.70710678118654752f;
  const float t = 1.0f / (1.0f + 0.3275911f * z);
  const float poly =
      t * (0.254829592f +
           t * (-0.284496736f +
                t * (1.421413741f + t * (-1.453152027f + t * 1.061405429f))));
  const float e = exp2f(-z * z * 1.4426950408889634f);
  const float erfz = 1.0f - poly * e;
  const float s = (x >= 0.f) ? erfz : -erfz;
  return 0.5f * x * (1.0f + s);
}

// ---------------- workspace layout (bytes) ----------------
#define QW_OFF   ((size_t)0)
#define KW_OFF   ((size_t)8 << 20)
#define VBUF_OFF ((size_t)16 << 20)
#define O1_OFF   ((size_t)24 << 20)   // bf16 normalized partials, 8MB
#define O2_OFF   ((size_t)40 << 20)
#define SRCB_OFF ((size_t)64 << 20)
#define L1_OFF   ((size_t)80 << 20)
#define L2P_OFF  (((size_t)80 << 20) + 131072)
#define WQT_OFF  (((size_t)80 << 20) + 262144)
#define WKT_OFF  (WQT_OFF + 32768)
#define WVT_OFF  (WQT_OFF + 65536)
#define WMT_OFF  (WQT_OFF + 98304)
#define W1T_OFF  (WQT_OFF + 131072)
#define W2T_OFF  (WQT_OFF + 655360)

// ---------------- kernel 0: transpose weights to bf16 [n][k]; scale folded into Wq ----
__global__ void k_prep(const float* __restrict__ wq, const float* __restrict__ wk,
                       const float* __restrict__ wv, const float* __restrict__ wm,
                       const float* __restrict__ w1, const float* __restrict__ w2,
                       u16* __restrict__ wqt, u16* __restrict__ wkt,
                       u16* __restrict__ wvt, u16* __restrict__ wmt,
                       u16* __restrict__ w1t, u16* __restrict__ w2t) {
  int t = blockIdx.x * 256 + threadIdx.x;
  if (t < 65536) {
    int m = t >> 14, loc = t & 16383;
    int n = loc >> 7, k = loc & 127;
    const float* s = (m == 0) ? wq : (m == 1) ? wk : (m == 2) ? wv : wm;
    u16* d = (m == 0) ? wqt : (m == 1) ? wkt : (m == 2) ? wvt : wmt;
    const float sc = (m == 0) ? 0.08838834764831845f : 1.0f;
    d[n * 128 + k] = f2b(s[k * 128 + n] * sc);
  } else if (t < 65536 + 262144) {
    int loc = t - 65536;
    int n = loc >> 8, k = loc & 255;
    w1t[n * 256 + k] = f2b(w1[k * 1024 + n]);
  } else if (t < 65536 + 262144 + 131072) {
    int loc = t - 327680;
    int n = loc >> 10, k = loc & 1023;
    w2t[n * 1024 + k] = f2b(w2[k * 128 + n]);
  }
}

// ---------------- kernel 1: QKV projection (R4 structure; 3 blocks/CU allowed) -------
__global__ __launch_bounds__(256, 3)
void k_qkv(const float* __restrict__ src,
           const u16* __restrict__ wtq, const u16* __restrict__ wtk,
           const u16* __restrict__ wtv,
           u16* __restrict__ qw, u16* __restrict__ kw, u16* __restrict__ vbuf,
           u16* __restrict__ srcb) {
  __shared__ __align__(16) u16 At[64 * 136];
  __shared__ __align__(16) u16 Bt[128 * 136];
  const int tid = threadIdx.x, bid = blockIdx.x;
  const int lane = tid & 63, wid = tid >> 6;
  const int l15 = lane & 15, quad = lane >> 4;

  {  // stage A tile (64 windowed rows x 128) + write srcb at original rows
    const int row = tid >> 2, part = tid & 3;
    const int t = bid * 64 + row;
    const int g = t >> 11, p = t & 2047;
    const int b = g >> 2, wi = (g >> 1) & 1, wj = g & 1;
    const int ii = p >> 6, jj = p & 63;
    const int y = (wi * 32 + ii + 16) & 63;
    const int x = (wj * 64 + jj + 32) & 127;
    const int srow = b * 8192 + y * 128 + x;
    const float4* sp = (const float4*)(src + srow * 128) + part * 8;
    u16* lp = &At[row * 136 + part * 32];
    u16* gp = srcb + srow * 128 + part * 32;
#pragma unroll
    for (int q = 0; q < 8; ++q) {
      float4 v = sp[q];
      ushort4 h = make_ushort4(f2b(v.x), f2b(v.y), f2b(v.z), f2b(v.w));
      *(ushort4*)(lp + q * 4) = h;
      *(ushort4*)(gp + q * 4) = h;
    }
  }
  __syncthreads();

  bf16x8 afrag[4];
  const int arow = wid * 16 + l15;
#pragma unroll
  for (int kk = 0; kk < 4; ++kk)
    afrag[kk] = *(const bf16x8*)&At[arow * 136 + kk * 32 + quad * 8];

  const f32x4 fz = {0.f, 0.f, 0.f, 0.f};
#pragma unroll 1
  for (int m = 0; m < 3; ++m) {
    const u16* wp = (m == 0) ? wtq : (m == 1) ? wtk : wtv;
    {  // stage B: weight [n][k] 128x128 bf16
      const int n = tid >> 1, half = tid & 1;
      const uint4* sp = (const uint4*)(wp + n * 128 + half * 64);
      uint4* dp = (uint4*)&Bt[n * 136 + half * 64];
#pragma unroll
      for (int q = 0; q < 8; ++q) dp[q] = sp[q];
    }
    __syncthreads();
    f32x4 acc[8];
#pragma unroll
    for (int nt = 0; nt < 8; ++nt) acc[nt] = fz;
#pragma unroll
    for (int kk = 0; kk < 4; ++kk) {
#pragma unroll
      for (int nt = 0; nt < 8; ++nt) {
        bf16x8 bfr = *(const bf16x8*)&Bt[(nt * 16 + l15) * 136 + kk * 32 + quad * 8];
        acc[nt] = MFMA(afrag[kk], bfr, acc[nt]);
      }
    }
    const int t0 = bid * 64 + wid * 16 + quad * 4;
    if (m < 2) {
      u16* dst = (m == 0) ? qw : kw;
#pragma unroll
      for (int nt = 0; nt < 8; ++nt) {
        const int d = nt * 16 + l15;
#pragma unroll
        for (int r = 0; r < 4; ++r) dst[(t0 + r) * 128 + d] = f2b(acc[nt][r]);
      }
    } else {
      const int g = bid >> 5;
      const int p0 = t0 & 2047;
#pragma unroll
      for (int nt = 0; nt < 8; ++nt) {
        const int d = nt * 16 + l15;
        ushort4 hv = make_ushort4(f2b(acc[nt][0]), f2b(acc[nt][1]),
                                  f2b(acc[nt][2]), f2b(acc[nt][3]));
        *(ushort4*)&vbuf[g * 262144 + d * 2048 + p0] = hv;
      }
    }
    __syncthreads();
  }
}

// ---------------- kernel 2: attention, 32 q-rows/wave, 64-key dbuf tiles (R4) --------
__global__ __launch_bounds__(256, 2)
void k_attn(const u16* __restrict__ qw, const u16* __restrict__ kw,
            const u16* __restrict__ vbuf, const float* __restrict__ mask,
            u16* __restrict__ o1, u16* __restrict__ o2,
            float* __restrict__ l1, float* __restrict__ l2) {
  __shared__ __align__(16) u16 Kt[2][64 * 128];  // [key][d], block swizzle c^=(key&15)
  __shared__ __align__(16) u16 Vt[2][128 * 64];  // [d][key], block swizzle c^=(d&7)
  __shared__ __align__(16) u16 Pt[128 * 40];     // per-wave P (32 rows x 32 keys)
  const int tid = threadIdx.x;
  const int bid = (blockIdx.x & 7) * 64 + (blockIdx.x >> 3);
  const int lane = tid & 63, wid = tid >> 6;
  const int l15 = lane & 15, quad = lane >> 4;
  const int b = bid & 3, w = (bid >> 2) & 3, half = (bid >> 4) & 1, qb = bid >> 5;
  const int g = b * 4 + w;
  const int k0 = half * 1024;
  const u16* kbase = kw + g * 262144 + k0 * 128;
  const u16* vbase = vbuf + g * 262144 + k0;
  const int qrow0 = qb * 128 + wid * 32;  // wave's first q-row within g
  const float* mlane = mask + (size_t)w * 4194304 + (size_t)(qrow0 + quad * 4) * 2048 + k0 + l15;

  // glds: per-thread source offsets (elems) + wave-uniform dest bases (elems)
  int offk[4], offv[4], dstb[4];
#pragma unroll
  for (int j = 0; j < 4; ++j) {
    const int s = wid * 256 + j * 64 + lane;         // linear 16B-block id, 0..1023
    const int rk = s >> 4, bk = (s & 15) ^ (rk & 15);
    offk[j] = rk * 128 + bk * 8;
    const int dv = s >> 3, bv = (s & 7) ^ (dv & 7);
    offv[j] = dv * 2048 + bv * 8;
    dstb[j] = (wid * 256 + j * 64) * 8;              // + lane*16B by hardware
  }

  bf16x8 qfrag[2][4];
#pragma unroll
  for (int qs = 0; qs < 2; ++qs) {
    const u16* qp = qw + g * 262144 + (qrow0 + qs * 16 + l15) * 128 + quad * 8;
#pragma unroll
    for (int kk = 0; kk < 4; ++kk) qfrag[qs][kk] = *(const bf16x8*)(qp + kk * 32);
  }
  const f32x4 fz = {0.f, 0.f, 0.f, 0.f};
  f32x4 o[2][8];
#pragma unroll
  for (int qs = 0; qs < 2; ++qs)
#pragma unroll
    for (int nt = 0; nt < 8; ++nt) o[qs][nt] = fz;
  float lr[2][4] = {{0.f, 0.f, 0.f, 0.f}, {0.f, 0.f, 0.f, 0.f}};
  const float L2E = 1.4426950408889634f;

  // preload tile 0 + mask phase 0 (mask double-buffered at 32-key phase granularity)
#pragma unroll
  for (int j = 0; j < 4; ++j) {
    glds16(kbase + offk[j], &Kt[0][dstb[j]]);
    glds16(vbase + offv[j], &Vt[0][dstb[j]]);
  }
  float mpf[16];
#pragma unroll
  for (int qs = 0; qs < 2; ++qs)
#pragma unroll
    for (int ntl = 0; ntl < 2; ++ntl)
#pragma unroll
      for (int r = 0; r < 4; ++r)
        mpf[qs * 8 + ntl * 4 + r] = mlane[(qs * 16 + r) * 2048 + ntl * 16];

#pragma unroll 1
  for (int kt = 0; kt < 16; ++kt) {
    const int p = kt & 1;
    __syncthreads();  // drains glds(kt) [issued a full iter ago]; prior-iter reads done
    if (kt < 15) {    // prefetch tile kt+1 into the other buffer; overlaps this compute
      const u16* kb = kbase + (kt + 1) * 8192;
      const u16* vb = vbase + (kt + 1) * 64;
#pragma unroll
      for (int j = 0; j < 4; ++j) {
        glds16(kb + offk[j], &Kt[p ^ 1][dstb[j]]);
        glds16(vb + offv[j], &Vt[p ^ 1][dstb[j]]);
      }
    }
#pragma unroll
    for (int ks = 0; ks < 2; ++ks) {
      // prefetch mask for the NEXT 32-key phase while computing this one
      float mn[16];
      const bool hasn = (kt < 15) || (ks == 0);
      const int ncol = kt * 64 + 32 + ks * 32;
      if (hasn) {
#pragma unroll
        for (int qs = 0; qs < 2; ++qs)
#pragma unroll
          for (int ntl = 0; ntl < 2; ++ntl)
#pragma unroll
            for (int r = 0; r < 4; ++r)
              mn[qs * 8 + ntl * 4 + r] = mlane[(qs * 16 + r) * 2048 + ncol + ntl * 16];
      }
      // S = Q K^T + mask (C-init from prefetched regs; Q pre-scaled)
      f32x4 s[2][2];
#pragma unroll
      for (int qs = 0; qs < 2; ++qs)
#pragma unroll
        for (int ntl = 0; ntl < 2; ++ntl)
#pragma unroll
          for (int r = 0; r < 4; ++r) s[qs][ntl][r] = mpf[qs * 8 + ntl * 4 + r];
#pragma unroll
      for (int kk = 0; kk < 4; ++kk)
#pragma unroll
        for (int ntl = 0; ntl < 2; ++ntl) {
          bf16x8 kfr = *(const bf16x8*)&Kt[p][(ks * 32 + ntl * 16 + l15) * 128 +
                                             (((kk * 4 + quad) ^ l15) * 8)];
          s[0][ntl] = MFMA(qfrag[0][kk], kfr, s[0][ntl]);
          s[1][ntl] = MFMA(qfrag[1][kk], kfr, s[1][ntl]);
        }
      // fixed-max softmax: p = e^s; per-lane partial row-sums (reduced in epilogue)
#pragma unroll
      for (int qs = 0; qs < 2; ++qs)
#pragma unroll
        for (int ntl = 0; ntl < 2; ++ntl)
#pragma unroll
          for (int r = 0; r < 4; ++r) {
            const float pv = exp2f(s[qs][ntl][r] * L2E);
            lr[qs][r] += pv;
            Pt[(wid * 32 + qs * 16 + quad * 4 + r) * 40 + ntl * 16 + l15] = f2b(pv);
          }
      // O += P @ V (P via per-wave LDS round-trip, C-layout -> A-layout)
      bf16x8 pf0 = *(const bf16x8*)&Pt[(wid * 32 + l15) * 40 + quad * 8];
      bf16x8 pf1 = *(const bf16x8*)&Pt[(wid * 32 + 16 + l15) * 40 + quad * 8];
#pragma unroll
      for (int nt = 0; nt < 8; ++nt) {
        bf16x8 vfr = *(const bf16x8*)&Vt[p][(nt * 16 + l15) * 64 +
                                            (((ks * 4 + quad) ^ (l15 & 7)) * 8)];
        o[0][nt] = MFMA(pf0, vfr, o[0][nt]);
        o[1][nt] = MFMA(pf1, vfr, o[1][nt]);
      }
      if (hasn) {
#pragma unroll
        for (int i = 0; i < 16; ++i) mpf[i] = mn[i];
      }
    }
  }

  // epilogue: reduce l across the 16 lanes, normalize partial, store bf16
#pragma unroll
  for (int off = 1; off < 16; off <<= 1)
#pragma unroll
    for (int qs = 0; qs < 2; ++qs)
#pragma unroll
      for (int r = 0; r < 4; ++r) lr[qs][r] += __shfl_xor(lr[qs][r], off, 16);
  u16* op = half ? o2 : o1;
  float* lp = half ? l2 : l1;
#pragma unroll
  for (int qs = 0; qs < 2; ++qs) {
    const int t0 = g * 2048 + qrow0 + qs * 16 + quad * 4;
#pragma unroll
    for (int r = 0; r < 4; ++r) {
      const float inv = 1.f / lr[qs][r];
#pragma unroll
      for (int nt = 0; nt < 8; ++nt)
        op[(size_t)(t0 + r) * 128 + nt * 16 + l15] = f2b(o[qs][nt][r] * inv);
      if (l15 == 0) lp[t0 + r] = lr[qs][r];
    }
  }
}

// ---------------- kernel 3: FUSED wmln+mlp (R7 structure + fast_gelu; R8-measured) ---
// out = src + LN2(gelu([src || LN1(merge(o1,o2)@Wm)] @ W1) @ W2).
__global__ __launch_bounds__(256, 2)
void k_mlp(const u16* __restrict__ o1, const u16* __restrict__ o2,
           const float* __restrict__ l1, const float* __restrict__ l2,
           const u16* __restrict__ wmt, const float* __restrict__ g1,
           const float* __restrict__ b1,
           const u16* __restrict__ srcb,
           const u16* __restrict__ w1t, const u16* __restrict__ w2t,
           const float* __restrict__ g2, const float* __restrict__ b2,
           const float* __restrict__ src, float* __restrict__ out) {
  __shared__ __align__(16) u16 lds[27136];          // 53KB overlay
  u16* Mt  = lds;                                   // ph1: 64*136 (8704)
  u16* BtW = lds + 8704;                            // ph1: 128*136 (17408)
  u16* Bt1 = lds;                                   // ph2: 2*32*256 (16384)
  u16* Bt2 = lds + 16384;                           // ph2: 2*128*32 (8192)
  u16* Ht  = lds + 24576;                           // ph2: 64*40 (2560)
  const int tid = threadIdx.x, bid = blockIdx.x;
  const int lane = tid & 63, wid = tid >> 6;
  const int l15 = lane & 15, quad = lane >> 4;
  const f32x4 fz = {0.f, 0.f, 0.f, 0.f};

  // A-frags [src half] issued early (global, spatial rows)
  bf16x8 afrag[8];
  {
    const int t_sp = bid * 64 + wid * 16 + l15;
    const u16* sp = srcb + (size_t)t_sp * 128 + quad * 8;
#pragma unroll
    for (int kk = 0; kk < 4; ++kk) afrag[kk] = *(const bf16x8*)(sp + kk * 32);
  }

  // ---- phase 1: stage merged message rows + Wm ----
  {
    const int row = tid >> 2, part = tid & 3;
    const int t_sp = bid * 64 + row;
    // spatial -> window row (inverse of k_qkv's to_windows)
    const int bb = t_sp >> 13, rem = t_sp & 8191;
    const int y = rem >> 7, x = rem & 127;
    const int u = (y + 48) & 63, v = (x + 96) & 127;
    const int wrow = (bb * 4 + (u >> 5) * 2 + (v >> 6)) * 2048 + (u & 31) * 64 + (v & 63);
    const float la = l1[wrow], lb = l2[wrow];
    const float wA = la / (la + lb), wB = lb / (la + lb);
    const u16* p1 = o1 + (size_t)wrow * 128 + part * 32;
    const u16* p2 = o2 + (size_t)wrow * 128 + part * 32;
    u16* lp = &Mt[row * 136 + part * 32];
#pragma unroll
    for (int q = 0; q < 4; ++q) {
      ushort4 xa = *(const ushort4*)(p1 + q * 8);
      ushort4 xb = *(const ushort4*)(p1 + q * 8 + 4);
      ushort4 ya = *(const ushort4*)(p2 + q * 8);
      ushort4 yb = *(const ushort4*)(p2 + q * 8 + 4);
      ushort4 ha = make_ushort4(f2b(b2f(xa.x) * wA + b2f(ya.x) * wB),
                                f2b(b2f(xa.y) * wA + b2f(ya.y) * wB),
                                f2b(b2f(xa.z) * wA + b2f(ya.z) * wB),
                                f2b(b2f(xa.w) * wA + b2f(ya.w) * wB));
      ushort4 hb = make_ushort4(f2b(b2f(xb.x) * wA + b2f(yb.x) * wB),
                                f2b(b2f(xb.y) * wA + b2f(yb.y) * wB),
                                f2b(b2f(xb.z) * wA + b2f(yb.z) * wB),
                                f2b(b2f(xb.w) * wA + b2f(yb.w) * wB));
      *(ushort4*)(lp + q * 8) = ha;
      *(ushort4*)(lp + q * 8 + 4) = hb;
    }
  }
  {
    const int n = tid >> 1, half = tid & 1;
    const uint4* sp = (const uint4*)(wmt + n * 128 + half * 64);
    uint4* dp = (uint4*)&BtW[n * 136 + half * 64];
#pragma unroll
    for (int q = 0; q < 8; ++q) dp[q] = sp[q];
  }
  __syncthreads();

  // Wm GEMM (16 rows x 128 cols per wave) + LN1
  {
    const int arow = wid * 16 + l15;
    bf16x8 am[4];
#pragma unroll
    for (int kk = 0; kk < 4; ++kk)
      am[kk] = *(const bf16x8*)&Mt[arow * 136 + kk * 32 + quad * 8];
    f32x4 acc[8];
#pragma unroll
    for (int nt = 0; nt < 8; ++nt) acc[nt] = fz;
#pragma unroll
    for (int kk = 0; kk < 4; ++kk)
#pragma unroll
      for (int nt = 0; nt < 8; ++nt) {
        bf16x8 bfr = *(const bf16x8*)&BtW[(nt * 16 + l15) * 136 + kk * 32 + quad * 8];
        acc[nt] = MFMA(am[kk], bfr, acc[nt]);
      }
    float sum[4] = {0, 0, 0, 0}, sq[4] = {0, 0, 0, 0};
#pragma unroll
    for (int nt = 0; nt < 8; ++nt)
#pragma unroll
      for (int r = 0; r < 4; ++r) {
        const float v = acc[nt][r];
        sum[r] += v;
        sq[r] += v * v;
      }
#pragma unroll
    for (int off = 1; off < 16; off <<= 1)
#pragma unroll
      for (int r = 0; r < 4; ++r) {
        sum[r] += __shfl_xor(sum[r], off, 16);
        sq[r] += __shfl_xor(sq[r], off, 16);
      }
    float mean[4], rstd[4];
#pragma unroll
    for (int r = 0; r < 4; ++r) {
      mean[r] = sum[r] * (1.f / 128.f);
      const float var = sq[r] * (1.f / 128.f) - mean[r] * mean[r];
      rstd[r] = rsqrtf(var + 1e-5f);
    }
    // write LN'd msg bf16 back into Mt (wave-private rows; MFMA reads already done)
#pragma unroll
    for (int nt = 0; nt < 8; ++nt) {
      const int d = nt * 16 + l15;
      const float gg = g1[d], bb = b1[d];
#pragma unroll
      for (int r = 0; r < 4; ++r)
        Mt[(wid * 16 + quad * 4 + r) * 136 + d] =
            f2b((acc[nt][r] - mean[r]) * rstd[r] * gg + bb);
    }
    // read msg A-frags (own rows; compiler orders via lgkmcnt)
#pragma unroll
    for (int kk = 0; kk < 4; ++kk)
      afrag[kk + 4] = *(const bf16x8*)&Mt[arow * 136 + kk * 32 + quad * 8];
  }
  __syncthreads();  // all msg A-frag reads done before phase-2 staging clobbers lds

  // ---- phase 2: MLP dbuf loop (R4-proven) ----
  int off1[4], db1[4], off2[2], db2[2];
#pragma unroll
  for (int j = 0; j < 4; ++j) {
    const int s = wid * 256 + j * 64 + lane;   // 16B-block id 0..1023
    const int r = s >> 5, c = s & 31;          // r: W1 row (hidden col), c: k-block
    off1[j] = r * 256 + (c ^ (r & 15)) * 8;
    db1[j] = (wid * 256 + j * 64) * 8;
  }
#pragma unroll
  for (int j = 0; j < 2; ++j) {
    const int s = wid * 128 + j * 64 + lane;   // 16B-block id 0..511
    const int r = s >> 2, c = s & 3;           // r: W2 row (d col), c: k-block
    off2[j] = r * 1024 + (c ^ (r & 3)) * 8;
    db2[j] = (wid * 128 + j * 64) * 8;
  }
  f32x4 oacc[8];
#pragma unroll
  for (int nt = 0; nt < 8; ++nt) oacc[nt] = fz;

  // prologue: stage chunk 0 into buffer 0
#pragma unroll
  for (int j = 0; j < 4; ++j) glds16(w1t + off1[j], &Bt1[db1[j]]);
#pragma unroll
  for (int j = 0; j < 2; ++j) glds16(w2t + off2[j], &Bt2[db2[j]]);

#pragma unroll 1
  for (int hc = 0; hc < 32; ++hc) {
    const int p = hc & 1;
    __syncthreads();  // drains glds(hc) [issued an iter ago]; prior-iter reads done
    if (hc < 31) {    // prefetch chunk hc+1 into the other buffer; overlaps compute
#pragma unroll
      for (int j = 0; j < 4; ++j)
        glds16(w1t + (hc + 1) * 8192 + off1[j], &Bt1[((p ^ 1) * 8192) + db1[j]]);
#pragma unroll
      for (int j = 0; j < 2; ++j)
        glds16(w2t + (hc + 1) * 32 + off2[j], &Bt2[((p ^ 1) * 4096) + db2[j]]);
    }

    // H chunk = A @ W1c  (16 rows x 32 cols per wave)
    f32x4 hacc[2];
    hacc[0] = fz;
    hacc[1] = fz;
#pragma unroll
    for (int kk = 0; kk < 8; ++kk)
#pragma unroll
      for (int nt = 0; nt < 2; ++nt) {
        bf16x8 b1fr = *(const bf16x8*)&Bt1[p * 8192 + (nt * 16 + l15) * 256 +
                                           (((kk * 4 + quad) ^ l15) * 8)];
        hacc[nt] = MFMA(afrag[kk], b1fr, hacc[nt]);
      }
    // fast_gelu -> bf16 Ht (per-wave rows; no barrier needed)
#pragma unroll
    for (int nt = 0; nt < 2; ++nt)
#pragma unroll
      for (int r = 0; r < 4; ++r) {
        const float y = fast_gelu(hacc[nt][r]);
        Ht[(wid * 16 + quad * 4 + r) * 40 + nt * 16 + l15] = f2b(y);
      }
    // out += Ht @ W2c
    bf16x8 hf = *(const bf16x8*)&Ht[(wid * 16 + l15) * 40 + quad * 8];
#pragma unroll
    for (int nt = 0; nt < 8; ++nt) {
      bf16x8 b2fr = *(const bf16x8*)&Bt2[p * 4096 + (nt * 16 + l15) * 32 +
                                         ((quad ^ (l15 & 3)) * 8)];
      oacc[nt] = MFMA(hf, b2fr, oacc[nt]);
    }
  }

  // LN2(g2,b2) + residual epilogue (fp32 out)
  float sum[4] = {0, 0, 0, 0}, sq[4] = {0, 0, 0, 0};
#pragma unroll
  for (int nt = 0; nt < 8; ++nt)
#pragma unroll
    for (int r = 0; r < 4; ++r) {
      const float v = oacc[nt][r];
      sum[r] += v;
      sq[r] += v * v;
    }
#pragma unroll
  for (int off = 1; off < 16; off <<= 1)
#pragma unroll
    for (int r = 0; r < 4; ++r) {
      sum[r] += __shfl_xor(sum[r], off, 16);
      sq[r] += __shfl_xor(sq[r], off, 16);
    }
  float mean[4], rstd[4];
#pragma unroll
  for (int r = 0; r < 4; ++r) {
    mean[r] = sum[r] * (1.f / 128.f);
    const float var = sq[r] * (1.f / 128.f) - mean[r] * mean[r];
    rstd[r] = rsqrtf(var + 1e-5f);
  }
  const int t0 = bid * 64 + wid * 16 + quad * 4;
#pragma unroll
  for (int nt = 0; nt < 8; ++nt) {
    const int d = nt * 16 + l15;
    const float gg = g2[d], bb = b2[d];
#pragma unroll
    for (int r = 0; r < 4; ++r) {
      const int idx = (t0 + r) * 128 + d;
      out[idx] = src[idx] + (oacc[nt][r] - mean[r]) * rstd[r] * gg + bb;
    }
  }
}

extern "C" void kernel_launch(void* const* d_in, const int* in_sizes, int n_in,
                              void* d_out, int out_size, void* d_ws, size_t ws_size,
                              hipStream_t stream) {
  const float* src  = (const float*)d_in[0];
  const float* mask = (const float*)d_in[2];
  const float* Wq = (const float*)d_in[8];
  const float* Wk = (const float*)d_in[9];
  const float* Wv = (const float*)d_in[10];
  const float* Wm = (const float*)d_in[11];
  const float* g1 = (const float*)d_in[12];
  const float* b1 = (const float*)d_in[13];
  const float* W1 = (const float*)d_in[14];
  const float* W2 = (const float*)d_in[15];
  const float* g2 = (const float*)d_in[16];
  const float* b2 = (const float*)d_in[17];
  char* ws = (char*)d_ws;
  u16* qw   = (u16*)(ws + QW_OFF);
  u16* kw   = (u16*)(ws + KW_OFF);
  u16* vbuf = (u16*)(ws + VBUF_OFF);
  u16* o1   = (u16*)(ws + O1_OFF);
  u16* o2   = (u16*)(ws + O2_OFF);
  float* l1 = (float*)(ws + L1_OFF);
  float* l2 = (float*)(ws + L2P_OFF);
  u16* srcb = (u16*)(ws + SRCB_OFF);
  u16* wqt = (u16*)(ws + WQT_OFF);
  u16* wkt = (u16*)(ws + WKT_OFF);
  u16* wvt = (u16*)(ws + WVT_OFF);
  u16* wmt = (u16*)(ws + WMT_OFF);
  u16* w1t = (u16*)(ws + W1T_OFF);
  u16* w2t = (u16*)(ws + W2T_OFF);

  k_prep<<<1792, 256, 0, stream>>>(Wq, Wk, Wv, Wm, W1, W2, wqt, wkt, wvt, wmt, w1t, w2t);
  k_qkv<<<512, 256, 0, stream>>>(src, wqt, wkt, wvt, qw, kw, vbuf, srcb);
  k_attn<<<512, 256, 0, stream>>>(qw, kw, vbuf, mask, o1, o2, l1, l2);
  k_mlp<<<512, 256, 0, stream>>>(o1, o2, l1, l2, wmt, g1, b1, srcb, w1t, w2t,
                                 g2, b2, src, (float*)d_out);
}

// Round 11
// 282.427 us; speedup vs baseline: 1.0596x; 1.0132x over previous
//
#include <hip/hip_runtime.h>

typedef unsigned short u16;
typedef __bf16 bf16x8 __attribute__((ext_vector_type(8)));
typedef float f32x4 __attribute__((ext_vector_type(4)));

#define MFMA(a, b, c) __builtin_amdgcn_mfma_f32_16x16x32_bf16(a, b, c, 0, 0, 0)

// Constants: B=4, H=64, W=128, D=128, NS=2, hh=32, ww=64, sh=16, sw=32,
// L=2048, 16 windows, 32768 rows total.

__device__ __forceinline__ u16 f2b(float f) {
  unsigned u = __builtin_bit_cast(unsigned, f);
  u += 0x7fffu + ((u >> 16) & 1u);
  return (u16)(u >> 16);
}
__device__ __forceinline__ float b2f(u16 h) {
  unsigned u = (unsigned)h << 16;
  return __builtin_bit_cast(float, u);
}
__device__ __forceinline__ void glds16(const u16* g, u16* l) {
  __builtin_amdgcn_global_load_lds((const __attribute__((address_space(1))) void*)g,
                                   (__attribute__((address_space(3))) void*)l, 16, 0, 0);
}
// gelu with branch-free erf (A&S 7.1.26, |err|<1.5e-7 — invisible after bf16 round).
__device__ __forceinline__ float fast_gelu(float x) {
  const float z = fabsf(x) * 0.70710678118654752f;
  const float t = 1.0f / (1.0f + 0.3275911f * z);
  const float poly =
      t * (0.254829592f +
           t * (-0.284496736f +
                t * (1.421413741f + t * (-1.453152027f + t * 1.061405429f))));
  const float e = exp2f(-z * z * 1.4426950408889634f);
  const float erfz = 1.0f - poly * e;
  const float s = (x >= 0.f) ? erfz : -erfz;
  return 0.5f * x * (1.0f + s);
}

// ---------------- workspace layout (bytes) ----------------
#define QW_OFF   ((size_t)0)
#define KW_OFF   ((size_t)8 << 20)
#define VBUF_OFF ((size_t)16 << 20)
#define O1_OFF   ((size_t)24 << 20)   // bf16 normalized partials, 8MB
#define O2_OFF   ((size_t)40 << 20)
#define SRCB_OFF ((size_t)64 << 20)
#define L1_OFF   ((size_t)80 << 20)
#define L2P_OFF  (((size_t)80 << 20) + 131072)
#define WQT_OFF  (((size_t)80 << 20) + 262144)
#define WKT_OFF  (WQT_OFF + 32768)
#define WVT_OFF  (WQT_OFF + 65536)
#define WMT_OFF  (WQT_OFF + 98304)
#define W1T_OFF  (WQT_OFF + 131072)
#define W2T_OFF  (WQT_OFF + 655360)

// ---------------- kernel 0: transpose weights to bf16 [n][k]; scale folded into Wq ----
__global__ void k_prep(const float* __restrict__ wq, const float* __restrict__ wk,
                       const float* __restrict__ wv, const float* __restrict__ wm,
                       const float* __restrict__ w1, const float* __restrict__ w2,
                       u16* __restrict__ wqt, u16* __restrict__ wkt,
                       u16* __restrict__ wvt, u16* __restrict__ wmt,
                       u16* __restrict__ w1t, u16* __restrict__ w2t) {
  int t = blockIdx.x * 256 + threadIdx.x;
  if (t < 65536) {
    int m = t >> 14, loc = t & 16383;
    int n = loc >> 7, k = loc & 127;
    const float* s = (m == 0) ? wq : (m == 1) ? wk : (m == 2) ? wv : wm;
    u16* d = (m == 0) ? wqt : (m == 1) ? wkt : (m == 2) ? wvt : wmt;
    const float sc = (m == 0) ? 0.08838834764831845f : 1.0f;
    d[n * 128 + k] = f2b(s[k * 128 + n] * sc);
  } else if (t < 65536 + 262144) {
    int loc = t - 65536;
    int n = loc >> 8, k = loc & 255;
    w1t[n * 256 + k] = f2b(w1[k * 1024 + n]);
  } else if (t < 65536 + 262144 + 131072) {
    int loc = t - 327680;
    int n = loc >> 10, k = loc & 1023;
    w2t[n * 1024 + k] = f2b(w2[k * 128 + n]);
  }
}

// ---------------- kernel 1: QKV projection (R11: glds dbuf weight chunks) ------------
// Weight staging moved to the attn/mlp-proven glds+dbuf pattern: 6 chunks of 64
// output-cols (3 m x 2 halves), Bt[2][64x128] with Kt-identical XOR swizzle
// (c ^= row&15), chunk c+1 staged async while chunk c computes. Removes the inline
// register round-trip (16 VMEM/LDS ops per thread per m) and serial stage->barrier->
// compute of the old single-buffer loop. LDS 49KB.
__global__ __launch_bounds__(256, 3)
void k_qkv(const float* __restrict__ src,
           const u16* __restrict__ wtq, const u16* __restrict__ wtk,
           const u16* __restrict__ wtv,
           u16* __restrict__ qw, u16* __restrict__ kw, u16* __restrict__ vbuf,
           u16* __restrict__ srcb) {
  __shared__ __align__(16) u16 At[64 * 136];     // 17.4KB, reg-staged (fp32 convert)
  __shared__ __align__(16) u16 Bt[2][64 * 128];  // 32KB, glds, swizzle c^=(row&15)
  const int tid = threadIdx.x, bid = blockIdx.x;
  const int lane = tid & 63, wid = tid >> 6;
  const int l15 = lane & 15, quad = lane >> 4;

  // glds offsets: 64x128 u16 chunk = 1024 16B-blocks, 4 per thread (Kt pattern)
  int offw[4], dstb[4];
#pragma unroll
  for (int j = 0; j < 4; ++j) {
    const int s = wid * 256 + j * 64 + lane;
    const int rk = s >> 4, bk = (s & 15) ^ (rk & 15);
    offw[j] = rk * 128 + bk * 8;
    dstb[j] = (wid * 256 + j * 64) * 8;  // + lane*16B by hardware
  }

  {  // stage A tile (64 windowed rows x 128) + write srcb at original rows
    const int row = tid >> 2, part = tid & 3;
    const int t = bid * 64 + row;
    const int g = t >> 11, p = t & 2047;
    const int b = g >> 2, wi = (g >> 1) & 1, wj = g & 1;
    const int ii = p >> 6, jj = p & 63;
    const int y = (wi * 32 + ii + 16) & 63;
    const int x = (wj * 64 + jj + 32) & 127;
    const int srow = b * 8192 + y * 128 + x;
    const float4* sp = (const float4*)(src + srow * 128) + part * 8;
    u16* lp = &At[row * 136 + part * 32];
    u16* gp = srcb + srow * 128 + part * 32;
#pragma unroll
    for (int q = 0; q < 8; ++q) {
      float4 v = sp[q];
      ushort4 h = make_ushort4(f2b(v.x), f2b(v.y), f2b(v.z), f2b(v.w));
      *(ushort4*)(lp + q * 4) = h;
      *(ushort4*)(gp + q * 4) = h;
    }
  }
  // prologue: stage chunk 0 (m=0, half=0) into Bt[0]
#pragma unroll
  for (int j = 0; j < 4; ++j) glds16(wtq + offw[j], &Bt[0][dstb[j]]);
  __syncthreads();  // A-tile writes visible; glds chunk 0 drained (vmcnt 0)

  bf16x8 afrag[4];
  const int arow = wid * 16 + l15;
#pragma unroll
  for (int kk = 0; kk < 4; ++kk)
    afrag[kk] = *(const bf16x8*)&At[arow * 136 + kk * 32 + quad * 8];

  const f32x4 fz = {0.f, 0.f, 0.f, 0.f};
  const int t0 = bid * 64 + wid * 16 + quad * 4;
#pragma unroll 1
  for (int c = 0; c < 6; ++c) {
    const int cb = c & 1;
    if (c < 5) {  // stage chunk c+1 into other buffer; overlaps this compute.
      // hazard: Bt[cb^1] last read in chunk c-1, protected by the barrier ending c-1.
      const int cn = c + 1;
      const u16* wp = ((cn >> 1) == 0 ? wtq : (cn >> 1) == 1 ? wtk : wtv) +
                      (cn & 1) * 8192;
#pragma unroll
      for (int j = 0; j < 4; ++j) glds16(wp + offw[j], &Bt[cb ^ 1][dstb[j]]);
    }
    f32x4 acc[4];
#pragma unroll
    for (int nt = 0; nt < 4; ++nt) acc[nt] = fz;
#pragma unroll
    for (int kk = 0; kk < 4; ++kk)
#pragma unroll
      for (int nt = 0; nt < 4; ++nt) {
        bf16x8 bfr = *(const bf16x8*)&Bt[cb][(nt * 16 + l15) * 128 +
                                            (((kk * 4 + quad) ^ l15) * 8)];
        acc[nt] = MFMA(afrag[kk], bfr, acc[nt]);
      }
    const int m = c >> 1, half = c & 1;
    if (m < 2) {
      u16* dst = (m == 0) ? qw : kw;
#pragma unroll
      for (int nt = 0; nt < 4; ++nt) {
        const int d = half * 64 + nt * 16 + l15;
#pragma unroll
        for (int r = 0; r < 4; ++r) dst[(t0 + r) * 128 + d] = f2b(acc[nt][r]);
      }
    } else {
      const int g = bid >> 5;
      const int p0 = t0 & 2047;
#pragma unroll
      for (int nt = 0; nt < 4; ++nt) {
        const int d = half * 64 + nt * 16 + l15;
        ushort4 hv = make_ushort4(f2b(acc[nt][0]), f2b(acc[nt][1]),
                                  f2b(acc[nt][2]), f2b(acc[nt][3]));
        *(ushort4*)&vbuf[g * 262144 + d * 2048 + p0] = hv;
      }
    }
    __syncthreads();  // reads of Bt[cb] done (next glds targets it) + glds c+1 drained
  }
}

// ---------------- kernel 2: attention, 32 q-rows/wave, 64-key dbuf tiles (R4) --------
__global__ __launch_bounds__(256, 2)
void k_attn(const u16* __restrict__ qw, const u16* __restrict__ kw,
            const u16* __restrict__ vbuf, const float* __restrict__ mask,
            u16* __restrict__ o1, u16* __restrict__ o2,
            float* __restrict__ l1, float* __restrict__ l2) {
  __shared__ __align__(16) u16 Kt[2][64 * 128];  // [key][d], block swizzle c^=(key&15)
  __shared__ __align__(16) u16 Vt[2][128 * 64];  // [d][key], block swizzle c^=(d&7)
  __shared__ __align__(16) u16 Pt[128 * 40];     // per-wave P (32 rows x 32 keys)
  const int tid = threadIdx.x;
  const int bid = (blockIdx.x & 7) * 64 + (blockIdx.x >> 3);
  const int lane = tid & 63, wid = tid >> 6;
  const int l15 = lane & 15, quad = lane >> 4;
  const int b = bid & 3, w = (bid >> 2) & 3, half = (bid >> 4) & 1, qb = bid >> 5;
  const int g = b * 4 + w;
  const int k0 = half * 1024;
  const u16* kbase = kw + g * 262144 + k0 * 128;
  const u16* vbase = vbuf + g * 262144 + k0;
  const int qrow0 = qb * 128 + wid * 32;  // wave's first q-row within g
  const float* mlane = mask + (size_t)w * 4194304 + (size_t)(qrow0 + quad * 4) * 2048 + k0 + l15;

  // glds: per-thread source offsets (elems) + wave-uniform dest bases (elems)
  int offk[4], offv[4], dstb[4];
#pragma unroll
  for (int j = 0; j < 4; ++j) {
    const int s = wid * 256 + j * 64 + lane;         // linear 16B-block id, 0..1023
    const int rk = s >> 4, bk = (s & 15) ^ (rk & 15);
    offk[j] = rk * 128 + bk * 8;
    const int dv = s >> 3, bv = (s & 7) ^ (dv & 7);
    offv[j] = dv * 2048 + bv * 8;
    dstb[j] = (wid * 256 + j * 64) * 8;              // + lane*16B by hardware
  }

  bf16x8 qfrag[2][4];
#pragma unroll
  for (int qs = 0; qs < 2; ++qs) {
    const u16* qp = qw + g * 262144 + (qrow0 + qs * 16 + l15) * 128 + quad * 8;
#pragma unroll
    for (int kk = 0; kk < 4; ++kk) qfrag[qs][kk] = *(const bf16x8*)(qp + kk * 32);
  }
  const f32x4 fz = {0.f, 0.f, 0.f, 0.f};
  f32x4 o[2][8];
#pragma unroll
  for (int qs = 0; qs < 2; ++qs)
#pragma unroll
    for (int nt = 0; nt < 8; ++nt) o[qs][nt] = fz;
  float lr[2][4] = {{0.f, 0.f, 0.f, 0.f}, {0.f, 0.f, 0.f, 0.f}};
  const float L2E = 1.4426950408889634f;

  // preload tile 0 + mask phase 0 (mask double-buffered at 32-key phase granularity)
#pragma unroll
  for (int j = 0; j < 4; ++j) {
    glds16(kbase + offk[j], &Kt[0][dstb[j]]);
    glds16(vbase + offv[j], &Vt[0][dstb[j]]);
  }
  float mpf[16];
#pragma unroll
  for (int qs = 0; qs < 2; ++qs)
#pragma unroll
    for (int ntl = 0; ntl < 2; ++ntl)
#pragma unroll
      for (int r = 0; r < 4; ++r)
        mpf[qs * 8 + ntl * 4 + r] = mlane[(qs * 16 + r) * 2048 + ntl * 16];

#pragma unroll 1
  for (int kt = 0; kt < 16; ++kt) {
    const int p = kt & 1;
    __syncthreads();  // drains glds(kt) [issued a full iter ago]; prior-iter reads done
    if (kt < 15) {    // prefetch tile kt+1 into the other buffer; overlaps this compute
      const u16* kb = kbase + (kt + 1) * 8192;
      const u16* vb = vbase + (kt + 1) * 64;
#pragma unroll
      for (int j = 0; j < 4; ++j) {
        glds16(kb + offk[j], &Kt[p ^ 1][dstb[j]]);
        glds16(vb + offv[j], &Vt[p ^ 1][dstb[j]]);
      }
    }
#pragma unroll
    for (int ks = 0; ks < 2; ++ks) {
      // prefetch mask for the NEXT 32-key phase while computing this one
      float mn[16];
      const bool hasn = (kt < 15) || (ks == 0);
      const int ncol = kt * 64 + 32 + ks * 32;
      if (hasn) {
#pragma unroll
        for (int qs = 0; qs < 2; ++qs)
#pragma unroll
          for (int ntl = 0; ntl < 2; ++ntl)
#pragma unroll
            for (int r = 0; r < 4; ++r)
              mn[qs * 8 + ntl * 4 + r] = mlane[(qs * 16 + r) * 2048 + ncol + ntl * 16];
      }
      // S = Q K^T + mask (C-init from prefetched regs; Q pre-scaled)
      f32x4 s[2][2];
#pragma unroll
      for (int qs = 0; qs < 2; ++qs)
#pragma unroll
        for (int ntl = 0; ntl < 2; ++ntl)
#pragma unroll
          for (int r = 0; r < 4; ++r) s[qs][ntl][r] = mpf[qs * 8 + ntl * 4 + r];
#pragma unroll
      for (int kk = 0; kk < 4; ++kk)
#pragma unroll
        for (int ntl = 0; ntl < 2; ++ntl) {
          bf16x8 kfr = *(const bf16x8*)&Kt[p][(ks * 32 + ntl * 16 + l15) * 128 +
                                             (((kk * 4 + quad) ^ l15) * 8)];
          s[0][ntl] = MFMA(qfrag[0][kk], kfr, s[0][ntl]);
          s[1][ntl] = MFMA(qfrag[1][kk], kfr, s[1][ntl]);
        }
      // fixed-max softmax: p = e^s; per-lane partial row-sums (reduced in epilogue)
#pragma unroll
      for (int qs = 0; qs < 2; ++qs)
#pragma unroll
        for (int ntl = 0; ntl < 2; ++ntl)
#pragma unroll
          for (int r = 0; r < 4; ++r) {
            const float pv = exp2f(s[qs][ntl][r] * L2E);
            lr[qs][r] += pv;
            Pt[(wid * 32 + qs * 16 + quad * 4 + r) * 40 + ntl * 16 + l15] = f2b(pv);
          }
      // O += P @ V (P via per-wave LDS round-trip, C-layout -> A-layout)
      bf16x8 pf0 = *(const bf16x8*)&Pt[(wid * 32 + l15) * 40 + quad * 8];
      bf16x8 pf1 = *(const bf16x8*)&Pt[(wid * 32 + 16 + l15) * 40 + quad * 8];
#pragma unroll
      for (int nt = 0; nt < 8; ++nt) {
        bf16x8 vfr = *(const bf16x8*)&Vt[p][(nt * 16 + l15) * 64 +
                                            (((ks * 4 + quad) ^ (l15 & 7)) * 8)];
        o[0][nt] = MFMA(pf0, vfr, o[0][nt]);
        o[1][nt] = MFMA(pf1, vfr, o[1][nt]);
      }
      if (hasn) {
#pragma unroll
        for (int i = 0; i < 16; ++i) mpf[i] = mn[i];
      }
    }
  }

  // epilogue: reduce l across the 16 lanes, normalize partial, store bf16
#pragma unroll
  for (int off = 1; off < 16; off <<= 1)
#pragma unroll
    for (int qs = 0; qs < 2; ++qs)
#pragma unroll
      for (int r = 0; r < 4; ++r) lr[qs][r] += __shfl_xor(lr[qs][r], off, 16);
  u16* op = half ? o2 : o1;
  float* lp = half ? l2 : l1;
#pragma unroll
  for (int qs = 0; qs < 2; ++qs) {
    const int t0 = g * 2048 + qrow0 + qs * 16 + quad * 4;
#pragma unroll
    for (int r = 0; r < 4; ++r) {
      const float inv = 1.f / lr[qs][r];
#pragma unroll
      for (int nt = 0; nt < 8; ++nt)
        op[(size_t)(t0 + r) * 128 + nt * 16 + l15] = f2b(o[qs][nt][r] * inv);
      if (l15 == 0) lp[t0 + r] = lr[qs][r];
    }
  }
}

// ---------------- kernel 3: FUSED wmln+mlp (R7 structure + fast_gelu; R8-measured) ---
// out = src + LN2(gelu([src || LN1(merge(o1,o2)@Wm)] @ W1) @ W2).
__global__ __launch_bounds__(256, 2)
void k_mlp(const u16* __restrict__ o1, const u16* __restrict__ o2,
           const float* __restrict__ l1, const float* __restrict__ l2,
           const u16* __restrict__ wmt, const float* __restrict__ g1,
           const float* __restrict__ b1,
           const u16* __restrict__ srcb,
           const u16* __restrict__ w1t, const u16* __restrict__ w2t,
           const float* __restrict__ g2, const float* __restrict__ b2,
           const float* __restrict__ src, float* __restrict__ out) {
  __shared__ __align__(16) u16 lds[27136];          // 53KB overlay
  u16* Mt  = lds;                                   // ph1: 64*136 (8704)
  u16* BtW = lds + 8704;                            // ph1: 128*136 (17408)
  u16* Bt1 = lds;                                   // ph2: 2*32*256 (16384)
  u16* Bt2 = lds + 16384;                           // ph2: 2*128*32 (8192)
  u16* Ht  = lds + 24576;                           // ph2: 64*40 (2560)
  const int tid = threadIdx.x, bid = blockIdx.x;
  const int lane = tid & 63, wid = tid >> 6;
  const int l15 = lane & 15, quad = lane >> 4;
  const f32x4 fz = {0.f, 0.f, 0.f, 0.f};

  // A-frags [src half] issued early (global, spatial rows)
  bf16x8 afrag[8];
  {
    const int t_sp = bid * 64 + wid * 16 + l15;
    const u16* sp = srcb + (size_t)t_sp * 128 + quad * 8;
#pragma unroll
    for (int kk = 0; kk < 4; ++kk) afrag[kk] = *(const bf16x8*)(sp + kk * 32);
  }

  // ---- phase 1: stage merged message rows + Wm ----
  {
    const int row = tid >> 2, part = tid & 3;
    const int t_sp = bid * 64 + row;
    // spatial -> window row (inverse of k_qkv's to_windows)
    const int bb = t_sp >> 13, rem = t_sp & 8191;
    const int y = rem >> 7, x = rem & 127;
    const int u = (y + 48) & 63, v = (x + 96) & 127;
    const int wrow = (bb * 4 + (u >> 5) * 2 + (v >> 6)) * 2048 + (u & 31) * 64 + (v & 63);
    const float la = l1[wrow], lb = l2[wrow];
    const float wA = la / (la + lb), wB = lb / (la + lb);
    const u16* p1 = o1 + (size_t)wrow * 128 + part * 32;
    const u16* p2 = o2 + (size_t)wrow * 128 + part * 32;
    u16* lp = &Mt[row * 136 + part * 32];
#pragma unroll
    for (int q = 0; q < 4; ++q) {
      ushort4 xa = *(const ushort4*)(p1 + q * 8);
      ushort4 xb = *(const ushort4*)(p1 + q * 8 + 4);
      ushort4 ya = *(const ushort4*)(p2 + q * 8);
      ushort4 yb = *(const ushort4*)(p2 + q * 8 + 4);
      ushort4 ha = make_ushort4(f2b(b2f(xa.x) * wA + b2f(ya.x) * wB),
                                f2b(b2f(xa.y) * wA + b2f(ya.y) * wB),
                                f2b(b2f(xa.z) * wA + b2f(ya.z) * wB),
                                f2b(b2f(xa.w) * wA + b2f(ya.w) * wB));
      ushort4 hb = make_ushort4(f2b(b2f(xb.x) * wA + b2f(yb.x) * wB),
                                f2b(b2f(xb.y) * wA + b2f(yb.y) * wB),
                                f2b(b2f(xb.z) * wA + b2f(yb.z) * wB),
                                f2b(b2f(xb.w) * wA + b2f(yb.w) * wB));
      *(ushort4*)(lp + q * 8) = ha;
      *(ushort4*)(lp + q * 8 + 4) = hb;
    }
  }
  {
    const int n = tid >> 1, half = tid & 1;
    const uint4* sp = (const uint4*)(wmt + n * 128 + half * 64);
    uint4* dp = (uint4*)&BtW[n * 136 + half * 64];
#pragma unroll
    for (int q = 0; q < 8; ++q) dp[q] = sp[q];
  }
  __syncthreads();

  // Wm GEMM (16 rows x 128 cols per wave) + LN1
  {
    const int arow = wid * 16 + l15;
    bf16x8 am[4];
#pragma unroll
    for (int kk = 0; kk < 4; ++kk)
      am[kk] = *(const bf16x8*)&Mt[arow * 136 + kk * 32 + quad * 8];
    f32x4 acc[8];
#pragma unroll
    for (int nt = 0; nt < 8; ++nt) acc[nt] = fz;
#pragma unroll
    for (int kk = 0; kk < 4; ++kk)
#pragma unroll
      for (int nt = 0; nt < 8; ++nt) {
        bf16x8 bfr = *(const bf16x8*)&BtW[(nt * 16 + l15) * 136 + kk * 32 + quad * 8];
        acc[nt] = MFMA(am[kk], bfr, acc[nt]);
      }
    float sum[4] = {0, 0, 0, 0}, sq[4] = {0, 0, 0, 0};
#pragma unroll
    for (int nt = 0; nt < 8; ++nt)
#pragma unroll
      for (int r = 0; r < 4; ++r) {
        const float v = acc[nt][r];
        sum[r] += v;
        sq[r] += v * v;
      }
#pragma unroll
    for (int off = 1; off < 16; off <<= 1)
#pragma unroll
      for (int r = 0; r < 4; ++r) {
        sum[r] += __shfl_xor(sum[r], off, 16);
        sq[r] += __shfl_xor(sq[r], off, 16);
      }
    float mean[4], rstd[4];
#pragma unroll
    for (int r = 0; r < 4; ++r) {
      mean[r] = sum[r] * (1.f / 128.f);
      const float var = sq[r] * (1.f / 128.f) - mean[r] * mean[r];
      rstd[r] = rsqrtf(var + 1e-5f);
    }
    // write LN'd msg bf16 back into Mt (wave-private rows; MFMA reads already done)
#pragma unroll
    for (int nt = 0; nt < 8; ++nt) {
      const int d = nt * 16 + l15;
      const float gg = g1[d], bb = b1[d];
#pragma unroll
      for (int r = 0; r < 4; ++r)
        Mt[(wid * 16 + quad * 4 + r) * 136 + d] =
            f2b((acc[nt][r] - mean[r]) * rstd[r] * gg + bb);
    }
    // read msg A-frags (own rows; compiler orders via lgkmcnt)
#pragma unroll
    for (int kk = 0; kk < 4; ++kk)
      afrag[kk + 4] = *(const bf16x8*)&Mt[arow * 136 + kk * 32 + quad * 8];
  }
  __syncthreads();  // all msg A-frag reads done before phase-2 staging clobbers lds

  // ---- phase 2: MLP dbuf loop (R4-proven) ----
  int off1[4], db1[4], off2[2], db2[2];
#pragma unroll
  for (int j = 0; j < 4; ++j) {
    const int s = wid * 256 + j * 64 + lane;   // 16B-block id 0..1023
    const int r = s >> 5, c = s & 31;          // r: W1 row (hidden col), c: k-block
    off1[j] = r * 256 + (c ^ (r & 15)) * 8;
    db1[j] = (wid * 256 + j * 64) * 8;
  }
#pragma unroll
  for (int j = 0; j < 2; ++j) {
    const int s = wid * 128 + j * 64 + lane;   // 16B-block id 0..511
    const int r = s >> 2, c = s & 3;           // r: W2 row (d col), c: k-block
    off2[j] = r * 1024 + (c ^ (r & 3)) * 8;
    db2[j] = (wid * 128 + j * 64) * 8;
  }
  f32x4 oacc[8];
#pragma unroll
  for (int nt = 0; nt < 8; ++nt) oacc[nt] = fz;

  // prologue: stage chunk 0 into buffer 0
#pragma unroll
  for (int j = 0; j < 4; ++j) glds16(w1t + off1[j], &Bt1[db1[j]]);
#pragma unroll
  for (int j = 0; j < 2; ++j) glds16(w2t + off2[j], &Bt2[db2[j]]);

#pragma unroll 1
  for (int hc = 0; hc < 32; ++hc) {
    const int p = hc & 1;
    __syncthreads();  // drains glds(hc) [issued an iter ago]; prior-iter reads done
    if (hc < 31) {    // prefetch chunk hc+1 into the other buffer; overlaps compute
#pragma unroll
      for (int j = 0; j < 4; ++j)
        glds16(w1t + (hc + 1) * 8192 + off1[j], &Bt1[((p ^ 1) * 8192) + db1[j]]);
#pragma unroll
      for (int j = 0; j < 2; ++j)
        glds16(w2t + (hc + 1) * 32 + off2[j], &Bt2[((p ^ 1) * 4096) + db2[j]]);
    }

    // H chunk = A @ W1c  (16 rows x 32 cols per wave)
    f32x4 hacc[2];
    hacc[0] = fz;
    hacc[1] = fz;
#pragma unroll
    for (int kk = 0; kk < 8; ++kk)
#pragma unroll
      for (int nt = 0; nt < 2; ++nt) {
        bf16x8 b1fr = *(const bf16x8*)&Bt1[p * 8192 + (nt * 16 + l15) * 256 +
                                           (((kk * 4 + quad) ^ l15) * 8)];
        hacc[nt] = MFMA(afrag[kk], b1fr, hacc[nt]);
      }
    // fast_gelu -> bf16 Ht (per-wave rows; no barrier needed)
#pragma unroll
    for (int nt = 0; nt < 2; ++nt)
#pragma unroll
      for (int r = 0; r < 4; ++r) {
        const float y = fast_gelu(hacc[nt][r]);
        Ht[(wid * 16 + quad * 4 + r) * 40 + nt * 16 + l15] = f2b(y);
      }
    // out += Ht @ W2c
    bf16x8 hf = *(const bf16x8*)&Ht[(wid * 16 + l15) * 40 + quad * 8];
#pragma unroll
    for (int nt = 0; nt < 8; ++nt) {
      bf16x8 b2fr = *(const bf16x8*)&Bt2[p * 4096 + (nt * 16 + l15) * 32 +
                                         ((quad ^ (l15 & 3)) * 8)];
      oacc[nt] = MFMA(hf, b2fr, oacc[nt]);
    }
  }

  // LN2(g2,b2) + residual epilogue (fp32 out)
  float sum[4] = {0, 0, 0, 0}, sq[4] = {0, 0, 0, 0};
#pragma unroll
  for (int nt = 0; nt < 8; ++nt)
#pragma unroll
    for (int r = 0; r < 4; ++r) {
      const float v = oacc[nt][r];
      sum[r] += v;
      sq[r] += v * v;
    }
#pragma unroll
  for (int off = 1; off < 16; off <<= 1)
#pragma unroll
    for (int r = 0; r < 4; ++r) {
      sum[r] += __shfl_xor(sum[r], off, 16);
      sq[r] += __shfl_xor(sq[r], off, 16);
    }
  float mean[4], rstd[4];
#pragma unroll
  for (int r = 0; r < 4; ++r) {
    mean[r] = sum[r] * (1.f / 128.f);
    const float var = sq[r] * (1.f / 128.f) - mean[r] * mean[r];
    rstd[r] = rsqrtf(var + 1e-5f);
  }
  const int t0 = bid * 64 + wid * 16 + quad * 4;
#pragma unroll
  for (int nt = 0; nt < 8; ++nt) {
    const int d = nt * 16 + l15;
    const float gg = g2[d], bb = b2[d];
#pragma unroll
    for (int r = 0; r < 4; ++r) {
      const int idx = (t0 + r) * 128 + d;
      out[idx] = src[idx] + (oacc[nt][r] - mean[r]) * rstd[r] * gg + bb;
    }
  }
}

extern "C" void kernel_launch(void* const* d_in, const int* in_sizes, int n_in,
                              void* d_out, int out_size, void* d_ws, size_t ws_size,
                              hipStream_t stream) {
  const float* src  = (const float*)d_in[0];
  const float* mask = (const float*)d_in[2];
  const float* Wq = (const float*)d_in[8];
  const float* Wk = (const float*)d_in[9];
  const float* Wv = (const float*)d_in[10];
  const float* Wm = (const float*)d_in[11];
  const float* g1 = (const float*)d_in[12];
  const float* b1 = (const float*)d_in[13];
  const float* W1 = (const float*)d_in[14];
  const float* W2 = (const float*)d_in[15];
  const float* g2 = (const float*)d_in[16];
  const float* b2 = (const float*)d_in[17];
  char* ws = (char*)d_ws;
  u16* qw   = (u16*)(ws + QW_OFF);
  u16* kw   = (u16*)(ws + KW_OFF);
  u16* vbuf = (u16*)(ws + VBUF_OFF);
  u16* o1   = (u16*)(ws + O1_OFF);
  u16* o2   = (u16*)(ws + O2_OFF);
  float* l1 = (float*)(ws + L1_OFF);
  float* l2 = (float*)(ws + L2P_OFF);
  u16* srcb = (u16*)(ws + SRCB_OFF);
  u16* wqt = (u16*)(ws + WQT_OFF);
  u16* wkt = (u16*)(ws + WKT_OFF);
  u16* wvt = (u16*)(ws + WVT_OFF);
  u16* wmt = (u16*)(ws + WMT_OFF);
  u16* w1t = (u16*)(ws + W1T_OFF);
  u16* w2t = (u16*)(ws + W2T_OFF);

  k_prep<<<1792, 256, 0, stream>>>(Wq, Wk, Wv, Wm, W1, W2, wqt, wkt, wvt, wmt, w1t, w2t);
  k_qkv<<<512, 256, 0, stream>>>(src, wqt, wkt, wvt, qw, kw, vbuf, srcb);
  k_attn<<<512, 256, 0, stream>>>(qw, kw, vbuf, mask, o1, o2, l1, l2);
  k_mlp<<<512, 256, 0, stream>>>(o1, o2, l1, l2, wmt, g1, b1, srcb, w1t, w2t,
                                 g2, b2, src, (float*)d_out);
}